// Round 1
// baseline (1420.842 us; speedup 1.0000x reference)
//
#include <hip/hip_runtime.h>

// QuantMatMul: fake-quant(A), fake-quant(B), batched matmul.
// A: [4,16,2048,64] f32, B: [4,16,64,2048] f32 -> C: [4,16,2048,2048] f32.
// Exactness: (q-zp) are integers in [-255,255] -> exact in bf16; products/sums
// exact in fp32 MFMA accumulator. C = dA*dB * sum((qa-zpA)*(qb-zpB)).

typedef __bf16 bf16_t;
typedef __bf16 bf16x4 __attribute__((ext_vector_type(4)));
typedef __bf16 bf16x8 __attribute__((ext_vector_type(8)));
typedef float f32x4 __attribute__((ext_vector_type(4)));

#define BATCH 64
#define MDIM 2048
#define NDIM 2048
#define KDIM 64

// Order-preserving float->uint mapping for integer min/max atomics.
__device__ __forceinline__ unsigned fmap(float x) {
    unsigned u = __float_as_uint(x);
    return (u & 0x80000000u) ? ~u : (u | 0x80000000u);
}
__device__ __forceinline__ float funmap(unsigned m) {
    return __uint_as_float((m & 0x80000000u) ? (m & 0x7fffffffu) : ~m);
}

__global__ void init_ws_kernel(unsigned* __restrict__ ws) {
    if (threadIdx.x < 4) ws[threadIdx.x] = 0x80000000u;  // fmap(0.0f): folds min(.,0)/max(.,0)
}

__global__ void minmax_kernel(const float4* __restrict__ A, const float4* __restrict__ B,
                              unsigned* __restrict__ ws, int n4, int blocksPerTensor) {
    bool isB = (int)blockIdx.x >= blocksPerTensor;
    const float4* __restrict__ src = isB ? B : A;
    unsigned* slot = ws + (isB ? 2 : 0);
    int bid = isB ? ((int)blockIdx.x - blocksPerTensor) : (int)blockIdx.x;
    float vmin = 0.0f, vmax = 0.0f;
    int stride = blocksPerTensor * blockDim.x;
    for (int i = bid * blockDim.x + threadIdx.x; i < n4; i += stride) {
        float4 v = src[i];
        vmin = fminf(vmin, fminf(fminf(v.x, v.y), fminf(v.z, v.w)));
        vmax = fmaxf(vmax, fmaxf(fmaxf(v.x, v.y), fmaxf(v.z, v.w)));
    }
#pragma unroll
    for (int off = 32; off > 0; off >>= 1) {
        vmin = fminf(vmin, __shfl_xor(vmin, off));
        vmax = fmaxf(vmax, __shfl_xor(vmax, off));
    }
    if ((threadIdx.x & 63) == 0) {
        atomicMin(&slot[0], fmap(vmin));
        atomicMax(&slot[1], fmap(vmax));
    }
}

// quantize-dequantize integer part: clamp(rint(x/d)+zp, 0, 255) - zp  (an integer in [-255,255])
__device__ __forceinline__ float qdq(float x, float rd, float zp) {
    float t = rintf(x * rd) + zp;
    t = fminf(fmaxf(t, 0.0f), 255.0f);
    return t - zp;
}

__global__ void __launch_bounds__(256)
qgemm_kernel(const float* __restrict__ A, const float* __restrict__ B,
             float* __restrict__ C, const unsigned* __restrict__ ws) {
    // LDS tiles: As[M=128][K=64], Bs[N=128][K=64] (B stored transposed), stride 72
    // (+8 pad) keeps every lane's 8-bf16 fragment read 16B-aligned (ds_read_b128).
    __shared__ __align__(16) bf16_t As[128][72];
    __shared__ __align__(16) bf16_t Bs[128][72];

    float minA = funmap(ws[0]), maxA = funmap(ws[1]);
    float minB = funmap(ws[2]), maxB = funmap(ws[3]);
    float dA = fmaxf((maxA - minA) / 255.0f, 1e-8f);
    float dB = fmaxf((maxB - minB) / 255.0f, 1e-8f);
    float zpA = rintf(-minA / dA);
    float zpB = rintf(-minB / dB);
    float rdA = 1.0f / dA;
    float rdB = 1.0f / dB;

    int tid = threadIdx.x;
    size_t z = blockIdx.z;
    const float* __restrict__ Ab = A + z * (size_t)(MDIM * KDIM) + (size_t)blockIdx.y * 128 * KDIM;
    const float* __restrict__ Bb = B + z * (size_t)(KDIM * NDIM) + (size_t)blockIdx.x * 128;

    // Stage A tile: 128 rows x 64 k, quantize to bf16 integers. 8 float4 per thread.
#pragma unroll
    for (int i = 0; i < 8; i++) {
        int c = tid + i * 256;          // 0..2047 float4 chunks
        int row = c >> 4;               // 16 float4 per row of 64
        int col4 = c & 15;
        float4 v = *(const float4*)(Ab + row * KDIM + col4 * 4);
        bf16x4 q;
        q[0] = (bf16_t)qdq(v.x, rdA, zpA);
        q[1] = (bf16_t)qdq(v.y, rdA, zpA);
        q[2] = (bf16_t)qdq(v.z, rdA, zpA);
        q[3] = (bf16_t)qdq(v.w, rdA, zpA);
        *(bf16x4*)(&As[row][col4 * 4]) = q;  // 8B LDS write
    }
    // Stage B tile transposed: global [k=64][n=128] -> LDS [n][k].
#pragma unroll
    for (int i = 0; i < 8; i++) {
        int c = tid + i * 256;          // 0..2047
        int k = c >> 5;                 // 32 float4 per k-row of 128 n
        int n4 = c & 31;
        float4 v = *(const float4*)(Bb + k * NDIM + n4 * 4);
        int n = n4 * 4;
        Bs[n + 0][k] = (bf16_t)qdq(v.x, rdB, zpB);
        Bs[n + 1][k] = (bf16_t)qdq(v.y, rdB, zpB);
        Bs[n + 2][k] = (bf16_t)qdq(v.z, rdB, zpB);
        Bs[n + 3][k] = (bf16_t)qdq(v.w, rdB, zpB);
    }
    __syncthreads();

    int wave = tid >> 6;
    int lane = tid & 63;
    int quad = lane >> 4;
    int l16 = lane & 15;
    int wm = (wave >> 1) * 64;   // wave's 64x64 sub-tile
    int wn = (wave & 1) * 64;

    // Fragments: A[m=lane&15][k=quad*8+j], B[n=lane&15][k=quad*8+j]; two K-halves.
    bf16x8 afrag[4][2], bfrag[4][2];
#pragma unroll
    for (int t = 0; t < 4; t++) {
#pragma unroll
        for (int h = 0; h < 2; h++) {
            afrag[t][h] = *(const bf16x8*)(&As[wm + t * 16 + l16][h * 32 + quad * 8]);
            bfrag[t][h] = *(const bf16x8*)(&Bs[wn + t * 16 + l16][h * 32 + quad * 8]);
        }
    }

    f32x4 acc[4][4];
#pragma unroll
    for (int tm = 0; tm < 4; tm++)
#pragma unroll
        for (int tn = 0; tn < 4; tn++) {
            f32x4 zero = {0.f, 0.f, 0.f, 0.f};
            acc[tm][tn] = zero;
        }

#pragma unroll
    for (int tm = 0; tm < 4; tm++) {
#pragma unroll
        for (int tn = 0; tn < 4; tn++) {
            acc[tm][tn] = __builtin_amdgcn_mfma_f32_16x16x32_bf16(afrag[tm][0], bfrag[tn][0], acc[tm][tn], 0, 0, 0);
            acc[tm][tn] = __builtin_amdgcn_mfma_f32_16x16x32_bf16(afrag[tm][1], bfrag[tn][1], acc[tm][tn], 0, 0, 0);
        }
    }

    // Epilogue: C/D layout col=lane&15, row=quad*4+reg. Scale by dA*dB.
    float scale = dA * dB;
    float* __restrict__ Cb = C + z * (size_t)(MDIM * NDIM) + (size_t)(blockIdx.y * 128) * NDIM + blockIdx.x * 128;
#pragma unroll
    for (int tm = 0; tm < 4; tm++) {
#pragma unroll
        for (int tn = 0; tn < 4; tn++) {
#pragma unroll
            for (int r = 0; r < 4; r++) {
                int row = wm + tm * 16 + quad * 4 + r;
                int col = wn + tn * 16 + l16;
                Cb[row * NDIM + col] = acc[tm][tn][r] * scale;
            }
        }
    }
}

extern "C" void kernel_launch(void* const* d_in, const int* in_sizes, int n_in,
                              void* d_out, int out_size, void* d_ws, size_t ws_size,
                              hipStream_t stream) {
    const float* A = (const float*)d_in[0];
    const float* B = (const float*)d_in[1];
    float* C = (float*)d_out;
    unsigned* ws = (unsigned*)d_ws;

    hipLaunchKernelGGL(init_ws_kernel, dim3(1), dim3(64), 0, stream, ws);

    int n4 = in_sizes[0] / 4;  // 2097152 float4 per tensor
    int bpt = 1024;            // blocks per tensor
    hipLaunchKernelGGL(minmax_kernel, dim3(2 * bpt), dim3(256), 0, stream,
                       (const float4*)A, (const float4*)B, ws, n4, bpt);

    dim3 grid(NDIM / 128, MDIM / 128, BATCH);  // (16,16,64)
    hipLaunchKernelGGL(qgemm_kernel, grid, dim3(256), 0, stream, A, B, C, ws);
}